// Round 4
// baseline (3918.584 us; speedup 1.0000x reference)
//
#include <hip/hip_runtime.h>

// VanillaRNN: h_{t+1} = tanh(W_hx x_t + W_hh h_t + b_h), T=1024, H=512, B=256.
// R17 = R16 with afrag pinned into the AGPR file ("a" constraint).
// R16 post-mortem: WRITE_SIZE 5.58 MB == one-time scratch spill of the
// "+v"-pinned afrag tuples (allocator capped arch VGPRs at 128 and would
// not cross-class-migrate 4-reg half8 tuples to AGPR; R13's 224 single
// dwords DID migrate). Step time 3.05us == L2-bound scratch re-read of
// ~425 KB/WG/step. Fix: pin afrag directly into AGPRs -- gfx950 MFMA
// reads the A operand natively from AGPR (cdna4_isa §10), 208 dwords
// <= 256 AGPR/wave cap at 2 waves/SIMD; arch VGPRs stay free for B
// loads, acc, addressing.
// Structure (unchanged from R16): 16 WGs x 16 batch cols, 1 WG/CU, 8
// identical MFMA waves; wave w owns rows [64w,64w+64) x full k -> no
// partial reduce, ONE barrier/step (dbuf h in LDS). B operand = 16
// different h vectors (100% N-slot use). C-init = whx*x+bh folded into
// MFMA. ksteps 0..12 of A in AGPRs, 13..15 in LDS (96 KB, lane-major
// conflict-free b128). x staged in 256-step chunks; final f32 h aliases
// the dead A-LDS region. LDS total 144.8 KB.
// Layout facts (HW-verified by R14/R15/R16 passing): A row = lane&15,
// k = 8*(lane>>4)+j; D col = lane&15, row = 4*(lane>>4)+q (m89); B
// symmetric to A. B-reads/A-reads at LDS structural optimum (8 dw/bank).
// Budget/step/CU: 512 MFMA x 4.85 cy = 2484 cy + tail/barrier ~500
// -> ~1.25 us/step -> ~1250-1400 us (R13 dot2 baseline: 1434).

#define T_SEQ    1024
#define HID      512
#define NTHREADS 512
#define NCLS     10
#define COLS     16     // batch columns per WG
#define NTILE    4      // 16-row tiles per wave (wave owns 64 rows)
#define KSTEPS   16     // 512 / 32
#define KREG     13     // ksteps 0..12 in AGPRs (208 dwords/lane)
#define KLDS     3      // ksteps 13..15 in LDS
#define HSTR     520    // _Float16 units; 260 dwords == 4 (mod 32)
#define HSB      (COLS * HSTR)   // 8320 f16 per h buffer
#define CHUNK    256    // x staging chunk (steps)
#define CHMASK   (CHUNK - 1)
#define XSTR_C   260    // floats per col in x chunk; == 4 (mod 32)
#define HFSTR    516    // floats; == 4 (mod 32)

// LDS layout (bytes)
#define OFF_HS    0                        // 2*8320*2        = 33280
#define OFF_ALDS  33280                    // 8*4*3*64*16     = 98304
#define OFF_XS    (33280 + 98304)          // 16*260*4        = 16640
#define SMEM_SZ   (OFF_XS + 16640)         // 148224 <= 163840

typedef _Float16 half2_t __attribute__((ext_vector_type(2)));
typedef _Float16 half8_t __attribute__((ext_vector_type(8)));
typedef float    f32x4_t __attribute__((ext_vector_type(4)));

#if __has_builtin(__builtin_amdgcn_sched_barrier)
#define SCHED_BARRIER() __builtin_amdgcn_sched_barrier(0)
#else
#define SCHED_BARRIER()
#endif

__device__ __forceinline__ unsigned int pack2(float a, float b) {
    half2_t h = {(_Float16)a, (_Float16)b};
    return __builtin_bit_cast(unsigned int, h);
}

__device__ __forceinline__ float fast_tanh(float s) {
    // tanh(s) = 1 - 2/(e^{2s}+1); exp2(s*2*log2e). Exact at +/-inf.
#if __has_builtin(__builtin_amdgcn_exp2f)
    float e = __builtin_amdgcn_exp2f(s * 2.885390081777927f);
#else
    float e = __expf(2.0f * s);
#endif
    return 1.0f - 2.0f / (e + 1.0f);
}

__global__ __attribute__((amdgpu_flat_work_group_size(NTHREADS, NTHREADS)))
           __attribute__((amdgpu_waves_per_eu(2, 2)))
void rnn_mfma(
    const float* __restrict__ x, const float* __restrict__ h_init,
    const float* __restrict__ W_hx, const float* __restrict__ W_hh,
    const float* __restrict__ b_h, const float* __restrict__ W_ph,
    const float* __restrict__ b_p, float* __restrict__ out)
{
    __shared__ __align__(16) unsigned char smem[SMEM_SZ];
    _Float16* hs   = (_Float16*)(smem + OFF_HS);    // [2][COLS*HSTR]
    uint4*    Alds = (uint4*)(smem + OFF_ALDS);     // [8][NTILE][KLDS][64]
    float*    xs   = (float*)(smem + OFF_XS);       // [COLS][XSTR_C]

    const int tid  = threadIdx.x;
    const int w    = tid >> 6;        // wave: owns rows [64w, 64w+64)
    const int lane = tid & 63;
    const int col  = lane & 15;       // MFMA M/N index (A row, B col, D col)
    const int g    = lane >> 4;       // k-group (8-wide chunk within k=32)
    const int col0 = blockIdx.x * COLS;

    // h_init broadcast to all 16 columns (reference broadcasts [H,1] -> [H,B]).
    for (int i = tid; i < COLS * HID; i += NTHREADS) {
        const int c = i >> 9, r = i & (HID - 1);
        hs[c * HSTR + r] = (_Float16)h_init[r];
    }

    // A fragments: lane (col,g) of wave w, tile tt holds
    // W_hh[64w+16tt+col][32ks+8g .. +8). ksteps 0..12 -> AGPRs ("a" pin
    // below; MFMA reads A natively from AGPR); 13..15 -> LDS (lane-major,
    // conflict-free b128).
    half8_t afrag[NTILE][KREG];
    float   whxr[NTILE][4], bhr[NTILE][4];
    #pragma unroll
    for (int tt = 0; tt < NTILE; ++tt) {
        const float* rowp = W_hh + (size_t)(64 * w + 16 * tt + col) * HID + 8 * g;
        #pragma unroll
        for (int ks = 0; ks < KREG; ++ks) {
            float4 v0 = *(const float4*)(rowp + 32 * ks);
            float4 v1 = *(const float4*)(rowp + 32 * ks + 4);
            half8_t a = {(_Float16)v0.x, (_Float16)v0.y, (_Float16)v0.z, (_Float16)v0.w,
                         (_Float16)v1.x, (_Float16)v1.y, (_Float16)v1.z, (_Float16)v1.w};
            afrag[tt][ks] = a;
            if ((ks & 3) == 3) SCHED_BARRIER();   // cap init-phase pressure
        }
        SCHED_BARRIER();
        #pragma unroll
        for (int ks = KREG; ks < KSTEPS; ++ks) {
            float4 v0 = *(const float4*)(rowp + 32 * ks);
            float4 v1 = *(const float4*)(rowp + 32 * ks + 4);
            Alds[((w * NTILE + tt) * KLDS + (ks - KREG)) * 64 + lane] =
                make_uint4(pack2(v0.x, v0.y), pack2(v0.z, v0.w),
                           pack2(v1.x, v1.y), pack2(v1.z, v1.w));
        }
        // D readout rows for this lane (m89 map): 4g+q within tile.
        #pragma unroll
        for (int q = 0; q < 4; ++q) {
            const int rr = 64 * w + 16 * tt + 4 * g + q;
            whxr[tt][q] = W_hx[rr];
            bhr[tt][q]  = b_h[rr];
        }
        SCHED_BARRIER();
    }
    // Pin A fragments into the AGPR file. "a" = AGPR constraint: forces the
    // packed values into accumulator registers once; the K-loop's MFMAs read
    // them from AGPR natively (no per-use copies, no arch-VGPR pressure).
    #pragma unroll
    for (int tt = 0; tt < NTILE; ++tt)
        #pragma unroll
        for (int ks = 0; ks < KREG; ++ks)
            asm volatile("" : "+a"(afrag[tt][ks]));

    __syncthreads();   // h_init + Alds visible

    f32x4_t acc[NTILE];   // lives past the loop: last step's sums feed epilogue

    #pragma unroll 1
    for (int t = 0; t < T_SEQ; ++t) {
        if ((t & CHMASK) == 0) {   // x chunk refill (4x over the loop)
            for (int i = tid; i < COLS * CHUNK; i += NTHREADS) {
                const int c = i >> 8, j = i & CHMASK;
                xs[c * XSTR_C + j] = x[(size_t)(col0 + c) * T_SEQ + t + j];
            }
            __syncthreads();
        }
        const int cur = t & 1;
        const _Float16* hb = hs + cur * HSB + col * HSTR + 8 * g;
        const float xw = xs[col * XSTR_C + (t & CHMASK)];

        // C-init = whx[row]*x_col[t] + bh[row] (folds input+bias into MFMA).
        #pragma unroll
        for (int tt = 0; tt < NTILE; ++tt) {
            f32x4_t a0;
            #pragma unroll
            for (int q = 0; q < 4; ++q) a0[q] = whxr[tt][q] * xw + bhr[tt][q];
            acc[tt] = a0;
        }

        // 64 MFMA/wave/step, 4 independent acc chains (x2 waves/SIMD = 8).
        #pragma unroll
        for (int ks = 0; ks < KREG; ++ks) {
            half8_t bf = *(const half8_t*)(hb + 32 * ks);
            #pragma unroll
            for (int tt = 0; tt < NTILE; ++tt)
                acc[tt] = __builtin_amdgcn_mfma_f32_16x16x32_f16(
                              afrag[tt][ks], bf, acc[tt], 0, 0, 0);
        }
        #pragma unroll
        for (int ks = KREG; ks < KSTEPS; ++ks) {
            half8_t bf = *(const half8_t*)(hb + 32 * ks);
            #pragma unroll
            for (int tt = 0; tt < NTILE; ++tt) {
                half8_t a = __builtin_bit_cast(half8_t,
                    Alds[((w * NTILE + tt) * KLDS + (ks - KREG)) * 64 + lane]);
                acc[tt] = __builtin_amdgcn_mfma_f32_16x16x32_f16(
                              a, bf, acc[tt], 0, 0, 0);
            }
        }

        // Tail: tanh + pack + publish h (lane owns D rows 4g..4g+3 of its col).
        _Float16* hn = hs + (cur ^ 1) * HSB + col * HSTR + 64 * w;
        #pragma unroll
        for (int tt = 0; tt < NTILE; ++tt) {
            const float v0 = fast_tanh(acc[tt][0]);
            const float v1 = fast_tanh(acc[tt][1]);
            const float v2 = fast_tanh(acc[tt][2]);
            const float v3 = fast_tanh(acc[tt][3]);
            *(uint2*)&hn[16 * tt + 4 * g] =
                make_uint2(pack2(v0, v1), pack2(v2, v3));
        }

        __syncthreads();   // dbuf hs => one barrier/step is sufficient
    }

    // Final h in f32: recompute tanh from the still-live last-step acc and
    // stage into the (now dead) A-LDS region. The loop's final barrier
    // guarantees all Alds reads are done before aliasing.
    float* hfin = (float*)(smem + OFF_ALDS);   // [COLS][HFSTR]
    #pragma unroll
    for (int tt = 0; tt < NTILE; ++tt) {
        const float v0 = fast_tanh(acc[tt][0]);
        const float v1 = fast_tanh(acc[tt][1]);
        const float v2 = fast_tanh(acc[tt][2]);
        const float v3 = fast_tanh(acc[tt][3]);
        *(float4*)&hfin[col * HFSTR + 64 * w + 16 * tt + 4 * g] =
            make_float4(v0, v1, v2, v3);
    }
    __syncthreads();

    // Epilogue: p = W_ph @ h_last + b_p for this WG's 16 columns.
    // Half-wave (32 lanes) per column: wave w handles cols 2w, 2w+1.
    {
        const int sub = lane >> 5, l32 = lane & 31;
        const int cl  = 2 * w + sub;          // 0..15
        #pragma unroll 1
        for (int c = 0; c < NCLS; ++c) {
            float s = 0.0f;
            #pragma unroll
            for (int j = 0; j < 16; ++j) {
                const int r = l32 + 32 * j;
                s += W_ph[c * HID + r] * hfin[cl * HFSTR + r];
            }
            #pragma unroll
            for (int off = 16; off; off >>= 1) s += __shfl_down(s, off, 64);
            if (l32 == 0) out[(size_t)(col0 + cl) * NCLS + c] = s + b_p[c];
        }
    }
}

extern "C" void kernel_launch(void* const* d_in, const int* in_sizes, int n_in,
                              void* d_out, int out_size, void* d_ws, size_t ws_size,
                              hipStream_t stream) {
    const float* x      = (const float*)d_in[0];
    const float* h_init = (const float*)d_in[1];
    const float* W_hx   = (const float*)d_in[2];
    const float* W_hh   = (const float*)d_in[3];
    const float* b_h    = (const float*)d_in[4];
    const float* W_ph   = (const float*)d_in[5];
    const float* b_p    = (const float*)d_in[6];
    float* out = (float*)d_out;

    const int B   = in_sizes[0] / T_SEQ;   // 256 batch columns
    const int nwg = B / COLS;              // 16 WGs, one per CU
    rnn_mfma<<<nwg, NTHREADS, 0, stream>>>(x, h_init, W_hx, W_hh, b_h, W_ph, b_p, out);
}

// Round 5
// 3259.804 us; speedup vs baseline: 1.2021x; 1.2021x over previous
//
#include <hip/hip_runtime.h>

// VanillaRNN: h_{t+1} = tanh(W_hx x_t + W_hh h_t + b_h), T=1024, H=512, B=256.
// R18: 4-wave WG at waves_per_eu(1,1) -> 512 regs/wave (256 VGPR + 256 AGPR).
// R16/R17 post-mortem: at 8 waves/CU the unified file caps at 256 regs/wave
// (128V+128A); afrag 208 dwords + working set = ~290 > 256 -> spill was
// ARITHMETICALLY FORCED (R17's "+a" demanded 208 > 128-AGPR ceiling).
// Fix: 256 thr/WG, 4 waves/CU, wave owns 128 rows (8 tiles):
//   - ksteps 0..7  -> AGPR, "+a"-pinned: 64 aligned quads = a0..a255 EXACTLY
//     (full AGPR occupancy also forces acc into VGPRs - protective)
//   - ksteps 8..12 -> VGPR (160 dwords); + acc 32 + temps ~30 = ~220/256
//   - ksteps 13..16 -> LDS (128 KB, lane-major conflict-free b128)
//   - bias+input FOLDED INTO K: h~=[h; x_t; 1; 0..], W~=[W_hh, w_hx, b_h, 0..]
//     K=544 = 17 ksteps; no C-init VALU, no whxr/bhr registers. x_{t+1}
//     prefetched from global by 16 lanes early each step, written into the
//     h-buffer slot 512 at the tail (b_h/w_hx/x in f16: |whx.x| <~ 0.4, f16
//     rel err 5e-4 -> below existing h-quantization error).
//   - h single-buffered in LDS (2 barriers/step), stride 584 f16
//     (dword-stride == 4 mod 32 -> b128 B-reads hit the 8/bank optimum)
// Structure: 16 WGs x 16 batch cols, 1 WG/CU, all-MFMA homogeneous waves;
// full-k accumulation -> no partial reduce. Layout facts (HW-verified by
// R14-R17 passing): A row = lane&15, k = 8*(lane>>4)+j; D col = lane&15,
// row = 4*(lane>>4)+q (m89); B symmetric to A.
// Budget/step/SIMD: 136 MFMA x 16-19 cy = 2200-2640 cy; LDS 196 KB/step =
// 1755 cy (separate pipe, covered); tail ~400 + 2 barriers ~150
// -> ~2900-3200 cy ~ 1.25 us/step -> ~1280-1380 us (R13 baseline: 1434).
// Tripwires: VGPR_Count >= 224 (attr took), WRITE_SIZE < 100 KB (no spill).

#define T_SEQ    1024
#define HID      512
#define NTHREADS 256
#define NWAVES   4
#define NCLS     10
#define COLS     16     // batch columns per WG (MFMA N)
#define NTILE    8      // 16-row tiles per wave (wave owns 128 rows)
#define KTOT     17     // ksteps: 544 = 512 h + x + 1 + 30 zeros
#define KAGPR    8      // ksteps 0..7  in AGPR (256 dwords, pinned)
#define KVGPR    5      // ksteps 8..12 in VGPR (160 dwords)
#define KLDS     4      // ksteps 13..16 in LDS
#define HSTR     584    // f16 stride; 584 % 64 == 8 -> dword stride == 4 mod 32
#define HFSTR    516    // f32 stride for final h; == 4 mod 32

// LDS layout (bytes)
#define OFF_ALDS  0                          // 4*8*4*64*16 = 131072
#define OFF_HS    131072                     // 16*584*2    = 18688
#define SMEM_SZ   (OFF_HS + 18688)           // 149760 <= 163840

typedef _Float16 half2_t __attribute__((ext_vector_type(2)));
typedef _Float16 half8_t __attribute__((ext_vector_type(8)));
typedef float    f32x4_t __attribute__((ext_vector_type(4)));

#if __has_builtin(__builtin_amdgcn_sched_barrier)
#define SCHED_BARRIER() __builtin_amdgcn_sched_barrier(0)
#else
#define SCHED_BARRIER()
#endif

__device__ __forceinline__ unsigned int pack2(float a, float b) {
    half2_t h = {(_Float16)a, (_Float16)b};
    return __builtin_bit_cast(unsigned int, h);
}

__device__ __forceinline__ float fast_tanh(float s) {
    // tanh(s) = 1 - 2/(e^{2s}+1); exp2(s*2*log2e). Exact at +/-inf.
#if __has_builtin(__builtin_amdgcn_exp2f)
    float e = __builtin_amdgcn_exp2f(s * 2.885390081777927f);
#else
    float e = __expf(2.0f * s);
#endif
    return 1.0f - 2.0f / (e + 1.0f);
}

__global__ __attribute__((amdgpu_flat_work_group_size(NTHREADS, NTHREADS)))
           __attribute__((amdgpu_waves_per_eu(1, 1)))
void rnn_mfma(
    const float* __restrict__ x, const float* __restrict__ h_init,
    const float* __restrict__ W_hx, const float* __restrict__ W_hh,
    const float* __restrict__ b_h, const float* __restrict__ W_ph,
    const float* __restrict__ b_p, float* __restrict__ out)
{
    __shared__ __align__(16) unsigned char smem[SMEM_SZ];
    uint4*    Alds = (uint4*)(smem + OFF_ALDS);   // [4][NTILE][KLDS][64]
    _Float16* hs   = (_Float16*)(smem + OFF_HS);  // [COLS][HSTR]

    const int tid  = threadIdx.x;
    const int w    = tid >> 6;        // wave 0..3: owns rows [128w, 128w+128)
    const int lane = tid & 63;
    const int col  = lane & 15;       // MFMA M/N index (A row, B col, D col)
    const int g    = lane >> 4;       // k-group (8-wide chunk within k=32)
    const int col0 = blockIdx.x * COLS;

    // h~ init: [h_init; x_0; 1; zeros] per column (h_init broadcasts to all).
    for (int c = 0; c < COLS; ++c)
        for (int r = tid; r < HSTR; r += NTHREADS) {
            float v = (r < HID) ? h_init[r] : 0.0f;
            if (r == HID)     v = x[(size_t)(col0 + c) * T_SEQ];   // x_0
            if (r == HID + 1) v = 1.0f;
            hs[c * HSTR + r] = (_Float16)v;
        }

    // A fragments: lane (col,g) of wave w, tile tt holds
    // W~[128w+16tt+col][32ks+8g .. +8). ks 0..7 -> AGPR (pinned immediately,
    // 64 quads = a0..a255 exactly); ks 8..12 -> VGPR; ks 13..15 -> LDS;
    // ks 16 (= [w_hx, b_h, zeros]) -> LDS.
    half8_t aA[NTILE][KAGPR];
    half8_t aV[NTILE][KVGPR];
    #pragma unroll
    for (int tt = 0; tt < NTILE; ++tt) {
        const int    row  = 128 * w + 16 * tt + col;
        const float* rowp = W_hh + (size_t)row * HID + 8 * g;
        #pragma unroll
        for (int ks = 0; ks < KAGPR; ++ks) {
            float4 v0 = *(const float4*)(rowp + 32 * ks);
            float4 v1 = *(const float4*)(rowp + 32 * ks + 4);
            half8_t a = {(_Float16)v0.x, (_Float16)v0.y, (_Float16)v0.z, (_Float16)v0.w,
                         (_Float16)v1.x, (_Float16)v1.y, (_Float16)v1.z, (_Float16)v1.w};
            aA[tt][ks] = a;
            asm volatile("" : "+a"(aA[tt][ks]));   // pin to AGPR now
        }
        SCHED_BARRIER();
        #pragma unroll
        for (int ks = 0; ks < KVGPR; ++ks) {
            float4 v0 = *(const float4*)(rowp + 32 * (KAGPR + ks));
            float4 v1 = *(const float4*)(rowp + 32 * (KAGPR + ks) + 4);
            half8_t a = {(_Float16)v0.x, (_Float16)v0.y, (_Float16)v0.z, (_Float16)v0.w,
                         (_Float16)v1.x, (_Float16)v1.y, (_Float16)v1.z, (_Float16)v1.w};
            aV[tt][ks] = a;
            asm volatile("" : "+v"(aV[tt][ks]));   // pin to VGPR
        }
        SCHED_BARRIER();
        #pragma unroll
        for (int ks = 0; ks < KLDS - 1; ++ks) {    // ksteps 13..15 (W_hh data)
            float4 v0 = *(const float4*)(rowp + 32 * (KAGPR + KVGPR + ks));
            float4 v1 = *(const float4*)(rowp + 32 * (KAGPR + KVGPR + ks) + 4);
            Alds[((w * NTILE + tt) * KLDS + ks) * 64 + lane] =
                make_uint4(pack2(v0.x, v0.y), pack2(v0.z, v0.w),
                           pack2(v1.x, v1.y), pack2(v1.z, v1.w));
        }
        {   // kstep 16: k in [512,544): [w_hx[row], b_h[row], 0, ...]
            float e[8];
            #pragma unroll
            for (int j = 0; j < 8; ++j) {
                const int k = HID + 8 * g + j - HID;   // local k-offset 8g+j
                float v = 0.0f;
                if (8 * g + j == 0) v = W_hx[row];
                if (8 * g + j == 1) v = b_h[row];
                e[j] = v;
            }
            Alds[((w * NTILE + tt) * KLDS + 3) * 64 + lane] =
                make_uint4(pack2(e[0], e[1]), pack2(e[2], e[3]),
                           pack2(e[4], e[5]), pack2(e[6], e[7]));
        }
        SCHED_BARRIER();
    }

    __syncthreads();   // h~ + Alds visible

    // Loop-invariant LDS bases.
    const _Float16* hb = hs + col * HSTR + 8 * g;          // B-frag base
    _Float16*       hn = hs + col * HSTR + 128 * w;        // h-write base
    const float*    xp = x + (size_t)(col0 + col) * T_SEQ; // x prefetch (w0 l<16)

    f32x4_t acc[NTILE];   // lives past the loop: last step's sums -> epilogue

    #pragma unroll 1
    for (int t = 0; t < T_SEQ; ++t) {
        // Prefetch x_{t+1} early (global, 16 lanes of wave 0); consumed at tail.
        float xnext = 0.0f;
        if (w == 0 && lane < COLS && t + 1 < T_SEQ) xnext = xp[t + 1];

        #pragma unroll
        for (int tt = 0; tt < NTILE; ++tt) acc[tt] = (f32x4_t){0.f, 0.f, 0.f, 0.f};

        // 136 MFMA/wave/step, 8 independent acc chains.
        #pragma unroll
        for (int ks = 0; ks < KAGPR; ++ks) {
            half8_t bf = *(const half8_t*)(hb + 32 * ks);
            #pragma unroll
            for (int tt = 0; tt < NTILE; ++tt)
                acc[tt] = __builtin_amdgcn_mfma_f32_16x16x32_f16(
                              aA[tt][ks], bf, acc[tt], 0, 0, 0);
        }
        #pragma unroll
        for (int ks = 0; ks < KVGPR; ++ks) {
            half8_t bf = *(const half8_t*)(hb + 32 * (KAGPR + ks));
            #pragma unroll
            for (int tt = 0; tt < NTILE; ++tt)
                acc[tt] = __builtin_amdgcn_mfma_f32_16x16x32_f16(
                              aV[tt][ks], bf, acc[tt], 0, 0, 0);
        }
        #pragma unroll
        for (int ks = 0; ks < KLDS; ++ks) {
            half8_t bf = *(const half8_t*)(hb + 32 * (KAGPR + KVGPR + ks));
            #pragma unroll
            for (int tt = 0; tt < NTILE; ++tt) {
                half8_t a = __builtin_bit_cast(half8_t,
                    Alds[((w * NTILE + tt) * KLDS + ks) * 64 + lane]);
                acc[tt] = __builtin_amdgcn_mfma_f32_16x16x32_f16(
                              a, bf, acc[tt], 0, 0, 0);
            }
        }

        __syncthreads();   // b1: all reads of hs done

        // Tail: tanh + pack + publish h_{t+1}; lane owns D rows 4g..4g+3.
        #pragma unroll
        for (int tt = 0; tt < NTILE; ++tt) {
            const float v0 = fast_tanh(acc[tt][0]);
            const float v1 = fast_tanh(acc[tt][1]);
            const float v2 = fast_tanh(acc[tt][2]);
            const float v3 = fast_tanh(acc[tt][3]);
            *(uint2*)&hn[16 * tt + 4 * g] =
                make_uint2(pack2(v0, v1), pack2(v2, v3));
        }
        if (w == 0 && lane < COLS)
            hs[lane * HSTR + HID] = (_Float16)xnext;   // x slot for step t+1

        __syncthreads();   // b2: writes visible
    }

    // Final h in f32 from the still-live last-step acc; stage into the dead
    // A-LDS region (all Alds reads completed before the loop's last b1).
    float* hfin = (float*)(smem + OFF_ALDS);   // [COLS][HFSTR]
    #pragma unroll
    for (int tt = 0; tt < NTILE; ++tt) {
        const float v0 = fast_tanh(acc[tt][0]);
        const float v1 = fast_tanh(acc[tt][1]);
        const float v2 = fast_tanh(acc[tt][2]);
        const float v3 = fast_tanh(acc[tt][3]);
        *(float4*)&hfin[col * HFSTR + 128 * w + 16 * tt + 4 * g] =
            make_float4(v0, v1, v2, v3);
    }
    __syncthreads();

    // Epilogue: p = W_ph @ h_last + b_p. Wave w covers cols 4w + (lane>>4);
    // 16 lanes per column, rows r = (lane&15) + 16j.
    {
        const int cl  = 4 * w + (lane >> 4);
        const int l16 = lane & 15;
        #pragma unroll 1
        for (int c = 0; c < NCLS; ++c) {
            float s = 0.0f;
            #pragma unroll
            for (int j = 0; j < 32; ++j) {
                const int r = l16 + 16 * j;
                s += W_ph[c * HID + r] * hfin[cl * HFSTR + r];
            }
            #pragma unroll
            for (int off = 8; off; off >>= 1) s += __shfl_down(s, off, 16);
            if (l16 == 0) out[(size_t)(col0 + cl) * NCLS + c] = s + b_p[c];
        }
    }
}

extern "C" void kernel_launch(void* const* d_in, const int* in_sizes, int n_in,
                              void* d_out, int out_size, void* d_ws, size_t ws_size,
                              hipStream_t stream) {
    const float* x      = (const float*)d_in[0];
    const float* h_init = (const float*)d_in[1];
    const float* W_hx   = (const float*)d_in[2];
    const float* W_hh   = (const float*)d_in[3];
    const float* b_h    = (const float*)d_in[4];
    const float* W_ph   = (const float*)d_in[5];
    const float* b_p    = (const float*)d_in[6];
    float* out = (float*)d_out;

    const int B   = in_sizes[0] / T_SEQ;   // 256 batch columns
    const int nwg = B / COLS;              // 16 WGs, one per CU
    rnn_mfma<<<nwg, NTHREADS, 0, stream>>>(x, h_init, W_hx, W_hh, b_h, W_ph, b_p, out);
}

// Round 6
// 2598.901 us; speedup vs baseline: 1.5078x; 1.2543x over previous
//
#include <hip/hip_runtime.h>

// VanillaRNN: h_{t+1} = tanh(W_hx x_t + W_hh h_t + b_h), T=1024, H=512, B=256.
// R19: 8 waves (2/SIMD) with a register plan that closes.
// R18 post-mortem: spill fixed (WRITE 10KB) but 1 wave/SIMD exposed all DS
// latency + tail (MfmaUtil 29% on active CUs, 7540 cy/step vs 2640 floor).
// Co-issue (R13 80% VALUBusy, m114) needs 2 waves/SIMD; R16 failed there by
// demanding 208 W-dwords/wave > 128V+128A cap. Feasible 8-wave split:
//   - wave w owns rows [64w,64w+64) (4 tiles), full k -> no partial reduce
//   - ksteps 0..7  -> AGPR, "+a"-pinned: 4*8*4 = 128 = AGPR cap EXACTLY
//     (R18 proved exact-fill + pin-immediately codegen at 256)
//   - ksteps 8..11 -> VGPR (64) + acc 16 (VGPR: C-init VALU touches it)
//   - ksteps 12..15 -> LDS (128 KB, lane-major conflict-free b128)
//   - h single-buffered (18.7 KB), 2 barriers/step
//   - K=512 un-folded; bias+input = C-init (16 fma) fed by a (W_hx,b_h)
//     LDS pair table read as FREE 16-lane broadcasts (4 KB)
//   - x_t: per-lane global prefetch one step ahead (16 lines/WG, L2-resident)
//   LDS total 153.9 KB <= 160 KB. VGPR ~124/128 (knife-edge; tripwire below).
// Layout facts (HW-verified, R14-R18 all passed): A row = lane&15,
// k = 8*(lane>>4)+j; D col = lane&15, row = 4*(lane>>4)+q (m89); B symmetric
// to A. B-reads: bank (4col+4g+16ks)%32 -> 8/bank = b128 structural optimum.
// Budget/step/SIMD: 2 waves x 64 MFMA x 19.4 cy = 2483 cy issue; DS latency
// + tanh tail co-hidden across the 2 waves -> ~2800-3100 cy ~ 1.2 us/step
// -> ~1200-1350 us (R13 baseline 1434; R18 3259).
// Tripwires: WRITE_SIZE < 100 KB (no spill); dur ~2x pred + high VALU =>
// per-use accvgpr_read copies => raw-asm MFMA next round.

#define T_SEQ    1024
#define HID      512
#define NTHREADS 512
#define NW       8
#define NCLS     10
#define COLS     16     // batch columns per WG (MFMA N)
#define NTILE    4      // 16-row tiles per wave (wave owns 64 rows)
#define KSTEPS   16     // 512 / 32
#define KAGPR    8      // ksteps 0..7  in AGPR (128 dwords = cap, pinned)
#define KVGPR    4      // ksteps 8..11 in VGPR (64 dwords, pinned)
#define KLDS     4      // ksteps 12..15 in LDS
#define HSTR     584    // f16 stride; dword stride 292 == 4 (mod 32)
#define HFSTR    516    // f32 stride for final h staging; == 4 (mod 32)

// LDS layout (bytes)
#define OFF_ALDS  0                          // 8*4*4*64*16 = 131072
#define OFF_HS    131072                     // 16*584*2    = 18688
#define OFF_WB    (131072 + 18688)           // 512*2*4     = 4096
#define SMEM_SZ   (OFF_WB + 4096)            // 153856 <= 163840

typedef _Float16 half2_t __attribute__((ext_vector_type(2)));
typedef _Float16 half8_t __attribute__((ext_vector_type(8)));
typedef float    f32x4_t __attribute__((ext_vector_type(4)));

#if __has_builtin(__builtin_amdgcn_sched_barrier)
#define SCHED_BARRIER() __builtin_amdgcn_sched_barrier(0)
#else
#define SCHED_BARRIER()
#endif

__device__ __forceinline__ unsigned int pack2(float a, float b) {
    half2_t h = {(_Float16)a, (_Float16)b};
    return __builtin_bit_cast(unsigned int, h);
}

__device__ __forceinline__ float fast_tanh(float s) {
    // tanh(s) = 1 - 2/(e^{2s}+1); exp2(s*2*log2e). Exact at +/-inf.
#if __has_builtin(__builtin_amdgcn_exp2f)
    float e = __builtin_amdgcn_exp2f(s * 2.885390081777927f);
#else
    float e = __expf(2.0f * s);
#endif
    return 1.0f - 2.0f / (e + 1.0f);
}

__global__ __attribute__((amdgpu_flat_work_group_size(NTHREADS, NTHREADS)))
           __attribute__((amdgpu_waves_per_eu(2, 2)))
void rnn_mfma(
    const float* __restrict__ x, const float* __restrict__ h_init,
    const float* __restrict__ W_hx, const float* __restrict__ W_hh,
    const float* __restrict__ b_h, const float* __restrict__ W_ph,
    const float* __restrict__ b_p, float* __restrict__ out)
{
    __shared__ __align__(16) unsigned char smem[SMEM_SZ];
    uint4*    Alds = (uint4*)(smem + OFF_ALDS);   // [NW][NTILE][KLDS][64]
    _Float16* hs   = (_Float16*)(smem + OFF_HS);  // [COLS][HSTR]
    float*    wb   = (float*)(smem + OFF_WB);     // [HID][2] = (whx, bh)

    const int tid  = threadIdx.x;
    const int w    = tid >> 6;        // wave 0..7: owns rows [64w, 64w+64)
    const int lane = tid & 63;
    const int col  = lane & 15;       // MFMA M/N index (A row, B col, D col)
    const int g    = lane >> 4;       // k-group (8-wide chunk within k=32)
    const int col0 = blockIdx.x * COLS;

    // h init (h_init broadcasts to all 16 columns, reference semantics).
    for (int i = tid; i < COLS * HID; i += NTHREADS) {
        const int c = i >> 9, r = i & (HID - 1);
        hs[c * HSTR + r] = (_Float16)h_init[r];
    }
    // (W_hx, b_h) pair table for the C-init broadcasts.
    for (int r = tid; r < HID; r += NTHREADS) {
        wb[2 * r]     = W_hx[r];
        wb[2 * r + 1] = b_h[r];
    }

    // A fragments: lane (col,g) of wave w, tile tt holds
    // W_hh[64w+16tt+col][32ks+8g .. +8). ks 0..7 -> AGPR (pinned per-kstep,
    // exact 128); ks 8..11 -> VGPR (pinned, 64); ks 12..15 -> LDS.
    half8_t aA[NTILE][KAGPR];
    half8_t aV[NTILE][KVGPR];
    #pragma unroll
    for (int tt = 0; tt < NTILE; ++tt) {
        const float* rowp = W_hh + (size_t)(64 * w + 16 * tt + col) * HID + 8 * g;
        #pragma unroll
        for (int ks = 0; ks < KAGPR; ++ks) {
            float4 v0 = *(const float4*)(rowp + 32 * ks);
            float4 v1 = *(const float4*)(rowp + 32 * ks + 4);
            half8_t a = {(_Float16)v0.x, (_Float16)v0.y, (_Float16)v0.z, (_Float16)v0.w,
                         (_Float16)v1.x, (_Float16)v1.y, (_Float16)v1.z, (_Float16)v1.w};
            aA[tt][ks] = a;
            asm volatile("" : "+a"(aA[tt][ks]));   // pin to AGPR immediately
        }
        SCHED_BARRIER();
        #pragma unroll
        for (int ks = 0; ks < KVGPR; ++ks) {
            float4 v0 = *(const float4*)(rowp + 32 * (KAGPR + ks));
            float4 v1 = *(const float4*)(rowp + 32 * (KAGPR + ks) + 4);
            half8_t a = {(_Float16)v0.x, (_Float16)v0.y, (_Float16)v0.z, (_Float16)v0.w,
                         (_Float16)v1.x, (_Float16)v1.y, (_Float16)v1.z, (_Float16)v1.w};
            aV[tt][ks] = a;
            asm volatile("" : "+v"(aV[tt][ks]));   // pin to VGPR
        }
        SCHED_BARRIER();
        #pragma unroll
        for (int ks = 0; ks < KLDS; ++ks) {        // ksteps 12..15
            float4 v0 = *(const float4*)(rowp + 32 * (KAGPR + KVGPR + ks));
            float4 v1 = *(const float4*)(rowp + 32 * (KAGPR + KVGPR + ks) + 4);
            Alds[((w * NTILE + tt) * KLDS + ks) * 64 + lane] =
                make_uint4(pack2(v0.x, v0.y), pack2(v0.z, v0.w),
                           pack2(v1.x, v1.y), pack2(v1.z, v1.w));
        }
        SCHED_BARRIER();
    }

    __syncthreads();   // h + Alds + wb visible

    // Loop-invariant bases.
    const _Float16* hb = hs + col * HSTR + 8 * g;          // B-frag base
    _Float16*       hn = hs + col * HSTR + 64 * w;         // h-write base
    const float*    xp = x + (size_t)(col0 + col) * T_SEQ; // per-lane x stream
    const float*    wbp = wb + 2 * (64 * w + 4 * g);       // C-init pair base

    f32x4_t acc[NTILE];   // survives the loop: last step's sums -> epilogue
    float xw = xp[0];

    #pragma unroll 1
    for (int t = 0; t < T_SEQ; ++t) {
        // Prefetch x_{t+1} (per-lane global, L2-resident; consumed next iter).
        const float xnext = xp[(t + 1 < T_SEQ) ? t + 1 : T_SEQ - 1];

        // C-init = whx[row]*x_col[t] + bh[row] via free 16-lane broadcasts
        // (address depends on (w,tt,g) only). Rows 64w+16tt+4g+{0..3}.
        #pragma unroll
        for (int tt = 0; tt < NTILE; ++tt) {
            const float4 p01 = *(const float4*)(wbp + 32 * tt);      // rows 4g,4g+1
            const float4 p23 = *(const float4*)(wbp + 32 * tt + 4);  // rows 4g+2,4g+3
            acc[tt][0] = p01.x * xw + p01.y;
            acc[tt][1] = p01.z * xw + p01.w;
            acc[tt][2] = p23.x * xw + p23.y;
            acc[tt][3] = p23.z * xw + p23.w;
        }

        // 64 MFMA/wave/step, 4 independent acc chains (x2 waves/SIMD = 8).
        #pragma unroll
        for (int ks = 0; ks < KAGPR; ++ks) {
            half8_t bf = *(const half8_t*)(hb + 32 * ks);
            #pragma unroll
            for (int tt = 0; tt < NTILE; ++tt)
                acc[tt] = __builtin_amdgcn_mfma_f32_16x16x32_f16(
                              aA[tt][ks], bf, acc[tt], 0, 0, 0);
            if (ks == 3) SCHED_BARRIER();   // cap B-temp hoisting (VGPR knife-edge)
        }
        SCHED_BARRIER();
        #pragma unroll
        for (int ks = 0; ks < KVGPR; ++ks) {
            half8_t bf = *(const half8_t*)(hb + 32 * (KAGPR + ks));
            #pragma unroll
            for (int tt = 0; tt < NTILE; ++tt)
                acc[tt] = __builtin_amdgcn_mfma_f32_16x16x32_f16(
                              aV[tt][ks], bf, acc[tt], 0, 0, 0);
        }
        #pragma unroll
        for (int ks = 0; ks < KLDS; ++ks) {
            half8_t bf = *(const half8_t*)(hb + 32 * (KAGPR + KVGPR + ks));
            #pragma unroll
            for (int tt = 0; tt < NTILE; ++tt) {
                half8_t a = __builtin_bit_cast(half8_t,
                    Alds[((w * NTILE + tt) * KLDS + ks) * 64 + lane]);
                acc[tt] = __builtin_amdgcn_mfma_f32_16x16x32_f16(
                              a, bf, acc[tt], 0, 0, 0);
            }
        }

        __syncthreads();   // b1: all reads of hs done

        // Tail: tanh + pack + publish h_{t+1}; lane owns D rows 4g..4g+3.
        #pragma unroll
        for (int tt = 0; tt < NTILE; ++tt) {
            const float v0 = fast_tanh(acc[tt][0]);
            const float v1 = fast_tanh(acc[tt][1]);
            const float v2 = fast_tanh(acc[tt][2]);
            const float v3 = fast_tanh(acc[tt][3]);
            *(uint2*)&hn[16 * tt + 4 * g] =
                make_uint2(pack2(v0, v1), pack2(v2, v3));
        }

        __syncthreads();   // b2: writes visible
        xw = xnext;
    }

    // Final h in f32 from the still-live last-step acc (C-init included);
    // stage into the dead A-LDS region (last b1/b2 fence all Alds reads).
    float* hfin = (float*)(smem + OFF_ALDS);   // [COLS][HFSTR]
    #pragma unroll
    for (int tt = 0; tt < NTILE; ++tt) {
        const float v0 = fast_tanh(acc[tt][0]);
        const float v1 = fast_tanh(acc[tt][1]);
        const float v2 = fast_tanh(acc[tt][2]);
        const float v3 = fast_tanh(acc[tt][3]);
        *(float4*)&hfin[col * HFSTR + 64 * w + 16 * tt + 4 * g] =
            make_float4(v0, v1, v2, v3);
    }
    __syncthreads();

    // Epilogue: p = W_ph @ h_last + b_p. Half-wave (32 lanes) per column:
    // wave w handles cols 2w, 2w+1 (reduction tree verified R16-clean).
    {
        const int sub = lane >> 5, l32 = lane & 31;
        const int cl  = 2 * w + sub;          // 0..15
        #pragma unroll 1
        for (int c = 0; c < NCLS; ++c) {
            float s = 0.0f;
            #pragma unroll
            for (int j = 0; j < 16; ++j) {
                const int r = l32 + 32 * j;
                s += W_ph[c * HID + r] * hfin[cl * HFSTR + r];
            }
            #pragma unroll
            for (int off = 16; off; off >>= 1) s += __shfl_down(s, off, 64);
            if (l32 == 0) out[(size_t)(col0 + cl) * NCLS + c] = s + b_p[c];
        }
    }
}

extern "C" void kernel_launch(void* const* d_in, const int* in_sizes, int n_in,
                              void* d_out, int out_size, void* d_ws, size_t ws_size,
                              hipStream_t stream) {
    const float* x      = (const float*)d_in[0];
    const float* h_init = (const float*)d_in[1];
    const float* W_hx   = (const float*)d_in[2];
    const float* W_hh   = (const float*)d_in[3];
    const float* b_h    = (const float*)d_in[4];
    const float* W_ph   = (const float*)d_in[5];
    const float* b_p    = (const float*)d_in[6];
    float* out = (float*)d_out;

    const int B   = in_sizes[0] / T_SEQ;   // 256 batch columns
    const int nwg = B / COLS;              // 16 WGs, one per CU
    rnn_mfma<<<nwg, NTHREADS, 0, stream>>>(x, h_init, W_hx, W_hh, b_h, W_ph, b_p, out);
}